// Round 4
// baseline (8976.310 us; speedup 1.0000x reference)
//
#include <hip/hip_runtime.h>
#include <hip/hip_bf16.h>
#include <cstdint>
#include <cstddef>

typedef __attribute__((ext_vector_type(8))) short bf16x8;
typedef __attribute__((ext_vector_type(4))) short bf16x4;
typedef __attribute__((ext_vector_type(4))) float f32x4;

#define LOG2E 1.442695041f

__device__ __forceinline__ float bf2f(short s){
  unsigned int u = ((unsigned int)(unsigned short)s) << 16;
  return __builtin_bit_cast(float, u);
}
__device__ __forceinline__ short f2bf(float f){
  unsigned int u = __builtin_bit_cast(unsigned int, f);
  unsigned int r = (u + 0x7fff + ((u >> 16) & 1)) >> 16;
  return (short)r;
}
__device__ __forceinline__ float sigm(float x){
  return __builtin_amdgcn_rcpf(1.f + __builtin_amdgcn_exp2f(-LOG2E * x));
}
__device__ __forceinline__ float tanh_(float x){
  return 1.f - 2.f * __builtin_amdgcn_rcpf(1.f + __builtin_amdgcn_exp2f(2.f * LOG2E * x));
}
// light workgroup barrier: drain LDS ops only, keep global loads in flight (T4)
__device__ __forceinline__ void wg_barrier(){
  asm volatile("s_waitcnt lgkmcnt(0)" ::: "memory");
  __builtin_amdgcn_s_barrier();
  asm volatile("" ::: "memory");
}
// permuted column np -> original gate column. np = w*256 + gate*64 + ul, orig = gate*256 + w*64 + ul
__device__ __forceinline__ int orig_col(int np){
  int w = np >> 8, rem = np & 255, gate = rem >> 6, ul = rem & 63;
  return gate * 256 + w * 64 + ul;
}

// ---------------- prep kernels ----------------
__global__ void k_prep_wipT(const float* __restrict__ Wi, short* __restrict__ outT, int K){
  int idx = blockIdx.x * 256 + threadIdx.x;      // over 1024*K/8
  int kv = K >> 3;
  int np = idx / kv, k0 = (idx % kv) * 8;
  int oc = orig_col(np);
  bf16x8 v;
  #pragma unroll
  for (int j = 0; j < 8; ++j) v[j] = f2bf(Wi[(size_t)(k0 + j) * 1024 + oc]);
  *(bf16x8*)(outT + (size_t)np * K + k0) = v;
}

__global__ void k_prep_bias(const float* __restrict__ b, float* __restrict__ bp){
  int np = blockIdx.x * 256 + threadIdx.x;
  bp[np] = b[orig_col(np)];
}

// Wh [256,1024] f32 -> frag-tiled bf16
__global__ void k_prep_wht(const float* __restrict__ Wh, short* __restrict__ wht){
  int idx = blockIdx.x * 256 + threadIdx.x;      // 32768 threads
  int l = idx & 63, fk = idx >> 6, kk = fk & 7, ng = fk >> 3;
  int oc = orig_col(ng * 16 + (l & 15));
  int kbase = kk * 32 + ((l >> 4) << 3);
  bf16x8 v;
  #pragma unroll
  for (int j = 0; j < 8; ++j) v[j] = f2bf(Wh[(size_t)(kbase + j) * 1024 + oc]);
  *(bf16x8*)(wht + (size_t)idx * 8) = v;
}

// embedding gather: x1t[(t*64+b)][k] = bf16(embed[tokens[b][t]][k])
__global__ void k_gather(const int* __restrict__ tokens, const float* __restrict__ embed,
                         short* __restrict__ x1t){
  int v = blockIdx.x * 256 + threadIdx.x;
  const int total = 64 * 1024 * 256 / 4;
  for (; v < total; v += gridDim.x * 256){
    int e = v * 4;
    int row = e >> 8, k = e & 255;
    int t = row >> 6, b = row & 63;
    int tok = tokens[b * 1024 + t];
    f32x4 f = *(const f32x4*)(embed + (size_t)tok * 256 + k);
    bf16x4 o4;
    #pragma unroll
    for (int j = 0; j < 4; ++j) o4[j] = f2bf(f[j]);
    *(bf16x4*)(x1t + e) = o4;
  }
}

// ---------------- input-projection GEMM (chunk of timesteps) ----------------
template<int K>
__global__ __launch_bounds__(256)
void k_gemm(const short* __restrict__ A, const short* __restrict__ BT,
            const float* __restrict__ bias, short* __restrict__ xw){
  __shared__ short ldsA[128 * 72];
  __shared__ short ldsB[128 * 72];
  int tid = threadIdx.x;
  int l = tid & 63, wid = tid >> 6, wm = wid >> 1, wn = wid & 1;
  int M0 = blockIdx.x * 128, N0 = blockIdx.y * 128;
  f32x4 acc[4][4] = {};
  for (int kt = 0; kt < K / 64; ++kt){
    __syncthreads();
    for (int i = tid; i < 1024; i += 256){
      int row = i >> 3, seg = i & 7;
      *(bf16x8*)&ldsA[row * 72 + seg * 8] = *(const bf16x8*)&A[(size_t)(M0 + row) * K + kt * 64 + seg * 8];
      *(bf16x8*)&ldsB[row * 72 + seg * 8] = *(const bf16x8*)&BT[(size_t)(N0 + row) * K + kt * 64 + seg * 8];
    }
    __syncthreads();
    #pragma unroll
    for (int kk = 0; kk < 2; ++kk){
      int koff = kk * 32 + ((l >> 4) << 3);
      bf16x8 af[4], bfm[4];
      #pragma unroll
      for (int mt = 0; mt < 4; ++mt) af[mt] = *(const bf16x8*)&ldsA[(wm * 64 + mt * 16 + (l & 15)) * 72 + koff];
      #pragma unroll
      for (int nt = 0; nt < 4; ++nt) bfm[nt] = *(const bf16x8*)&ldsB[(wn * 64 + nt * 16 + (l & 15)) * 72 + koff];
      #pragma unroll
      for (int mt = 0; mt < 4; ++mt)
        #pragma unroll
        for (int nt = 0; nt < 4; ++nt)
          acc[mt][nt] = __builtin_amdgcn_mfma_f32_16x16x32_bf16(af[mt], bfm[nt], acc[mt][nt], 0, 0, 0);
    }
  }
  int t = blockIdx.x * 2 + wm;   // chunk-local t
  #pragma unroll
  for (int mt = 0; mt < 4; ++mt){
    #pragma unroll
    for (int nt = 0; nt < 4; ++nt){
      int ng = (N0 >> 4) + wn * 4 + nt;
      float bs = bias[ng * 16 + (l & 15)];
      bf16x4 ov;
      #pragma unroll
      for (int r = 0; r < 4; ++r) ov[r] = f2bf(acc[mt][nt][r] + bs);
      *(bf16x4*)&xw[((size_t)(t * 4 + mt) * 64 + ng) * 256 + l * 4] = ov;
    }
  }
}

// ---------------- recurrence (chunk of S steps) ----------------
// One WG per (dir, batch-chunk-16). 4 waves, 1/SIMD. Wh: 91 frags/wave regs + 37/wave LDS.
// h in LDS in A-FRAGMENT layout: short idx = kk*512 + L*8 + j  <->  h[batch=L&15][unit=kk*32+(L>>4)*8+j]
template<int WRITE_SEQ>
__global__ __launch_bounds__(256, 1)
void k_recur(const short* __restrict__ xw_f, const short* __restrict__ xw_b,
             const short* __restrict__ wht_f, const short* __restrict__ wht_b,
             short* __restrict__ outp, float* __restrict__ cstate, short* __restrict__ hstate,
             int t0, int S, int two_dirs, int first)
{
  extern __shared__ char lds[];
  short* ldsB = (short*)lds;                 // 4 waves * 37 frags * 1024B = 151552
  char*  ldsH = lds + 151552;                // 8192B, A-layout
  int g = blockIdx.x;
  int d  = two_dirs ? (g >> 2) : 0;
  int cb = two_dirs ? (g & 3) : g;
  int blk = two_dirs ? (d * 4 + cb) : cb;    // state block index
  const short* xw  = d ? xw_b : xw_f;
  const short* wht = d ? wht_b : wht_f;
  int tid = threadIdx.x, w = tid >> 6, l = tid & 63;
  short* ldsBw = ldsB + (size_t)w * 37 * 64 * 8;

  // resident B fragments in regs: kk 0..4 all n (80) + kk==5 n<11 (11) = 91
  bf16x8 Breg[91];
  #pragma unroll
  for (int kk = 0; kk < 5; ++kk)
    #pragma unroll
    for (int n = 0; n < 16; ++n)
      Breg[kk * 16 + n] = *(const bf16x8*)&wht[(((size_t)(w * 16 + n) * 8 + kk) * 64 + l) * 8];
  #pragma unroll
  for (int n = 0; n < 11; ++n)
    Breg[80 + n] = *(const bf16x8*)&wht[(((size_t)(w * 16 + n) * 8 + 5) * 64 + l) * 8];

  // LDS B fragments: kk5 n11..15 -> slot 0..4 ; kk6 -> 5+n ; kk7 -> 21+n
  for (int s = 0; s < 37; ++s){
    int kk, n;
    if (s < 5)      { kk = 5; n = 11 + s; }
    else if (s < 21){ kk = 6; n = s - 5; }
    else            { kk = 7; n = s - 21; }
    *(bf16x8*)&ldsBw[(s * 64 + l) * 8] =
        *(const bf16x8*)&wht[(((size_t)(w * 16 + n) * 8 + kk) * 64 + l) * 8];
  }

  // h init (A-layout is linear -> plain copies) + c state
  f32x4 cst[4];
  if (first){
    *(bf16x8*)(ldsH + tid * 32)      = bf16x8{0,0,0,0,0,0,0,0};
    *(bf16x8*)(ldsH + tid * 32 + 16) = bf16x8{0,0,0,0,0,0,0,0};
    #pragma unroll
    for (int q = 0; q < 4; ++q) cst[q] = f32x4{0.f,0.f,0.f,0.f};
  } else {
    const char* hsrc = (const char*)hstate + (size_t)blk * 8192;
    *(bf16x8*)(ldsH + tid * 32)      = *(const bf16x8*)(hsrc + tid * 32);
    *(bf16x8*)(ldsH + tid * 32 + 16) = *(const bf16x8*)(hsrc + tid * 32 + 16);
    #pragma unroll
    for (int q = 0; q < 4; ++q)
      #pragma unroll
      for (int r = 0; r < 4; ++r){
        int batch = ((l >> 4) << 2) + r, unit = w * 64 + q * 16 + (l & 15);
        cst[q][r] = cstate[((size_t)blk * 16 + batch) * 256 + unit];
      }
  }
  __syncthreads();

  // per-thread LDS addresses
  char* afBase = ldsH + l * 16;                       // af[kk] at imm offset kk*1024
  char* hwBase = ldsH + (w * 2048 + ((l >> 4) << 6) + (((l >> 3) & 1) << 8) + ((l & 7) << 1));
  // seq-store decode (per thread)
  int skk = tid >> 5, sL = (tid & 31) * 2;
  long seqRow0_f = ((long)(d ? (1023 - t0) : t0) * 64 + cb * 16);
  short* seqP0 = WRITE_SEQ ? (outp + (seqRow0_f + (sL & 15)) * 512 + d * 256 + skk * 32 + ((sL >> 4) << 3)) : (short*)nullptr;
  short* seqP1 = WRITE_SEQ ? (outp + (seqRow0_f + ((sL + 1) & 15)) * 512 + d * 256 + skk * 32 + (((sL + 1) >> 4) << 3)) : (short*)nullptr;
  long seqStep = (d ? -1l : 1l) * 64 * 512;

  // x stream pointers
  long xwStep = (d ? -1l : 1l) * 4 * 64 * 256;
  const short* xwCur = xw + ((size_t)((d ? (S - 1) : 0) * 4 + cb) * 64) * 256;

  // first-step x prefetch
  bf16x4 px[16];
  #pragma unroll
  for (int n = 0; n < 16; ++n) px[n] = *(const bf16x4*)&xwCur[((w * 16 + n) * 64 + l) * 4];

  #pragma unroll 1
  for (int s = 0; s < S; ++s){
    const short* xwNext = (s + 1 < S) ? (xwCur + xwStep) : xwCur;

    // A fragments of h (contiguous, conflict-free)
    bf16x8 af[8];
    #pragma unroll
    for (int kk = 0; kk < 8; ++kk)
      af[kk] = *(const bf16x8*)(afBase + kk * 1024);
    wg_barrier();   // barrier A: all reads drained; writes may begin

    #pragma unroll
    for (int q = 0; q < 4; ++q){
      f32x4 acc[4];
      #pragma unroll
      for (int j = 0; j < 4; ++j){
        #pragma unroll
        for (int r = 0; r < 4; ++r) acc[j][r] = bf2f(px[4 * j + q][r]);
      }
      // refill this q's px slots for next step (full-step latency window)
      #pragma unroll
      for (int j = 0; j < 4; ++j)
        px[4 * j + q] = *(const bf16x4*)&xwNext[((w * 16 + 4 * j + q) * 64 + l) * 4];
      #pragma unroll
      for (int kk = 0; kk < 8; ++kk){
        #pragma unroll
        for (int j = 0; j < 4; ++j){
          int n = 4 * j + q;
          bf16x8 bfr;
          if (kk < 5)                  bfr = Breg[kk * 16 + n];
          else if (kk == 5 && n < 11)  bfr = Breg[80 + n];
          else {
            int slot = (kk == 5) ? (n - 11) : ((kk == 6) ? (5 + n) : (21 + n));
            bfr = *(const bf16x8*)&ldsBw[(slot * 64 + l) * 8];
          }
          acc[j] = __builtin_amdgcn_mfma_f32_16x16x32_bf16(af[kk], bfr, acc[j], 0, 0, 0);
        }
      }
      // gates: j = 0..3 -> i,f,g,o for unit w*64+q*16+(l&15), batch (l>>4)*4+r
      #pragma unroll
      for (int r = 0; r < 4; ++r){
        float ii = sigm(acc[0][r]), ff = sigm(acc[1][r]), gg = tanh_(acc[2][r]), oo = sigm(acc[3][r]);
        float cc = ff * cst[q][r] + ii * gg;
        cst[q][r] = cc;
        float hh = oo * tanh_(cc);
        *(short*)(hwBase + (q * 512 + r * 16)) = f2bf(hh);   // imm-offset ds_write_b16
      }
    }
    wg_barrier();   // barrier B: h complete

    if (WRITE_SEQ){
      bf16x8 h0 = *(const bf16x8*)(ldsH + tid * 32);
      bf16x8 h1 = *(const bf16x8*)(ldsH + tid * 32 + 16);
      *(bf16x8*)seqP0 = h0;
      *(bf16x8*)seqP1 = h1;
      seqP0 += seqStep; seqP1 += seqStep;
    }
    xwCur = xwNext;
  }

  // save state (A-layout, linear)
  {
    char* hdst = (char*)hstate + (size_t)blk * 8192;
    *(bf16x8*)(hdst + tid * 32)      = *(const bf16x8*)(ldsH + tid * 32);
    *(bf16x8*)(hdst + tid * 32 + 16) = *(const bf16x8*)(ldsH + tid * 32 + 16);
  }
  #pragma unroll
  for (int q = 0; q < 4; ++q)
    #pragma unroll
    for (int r = 0; r < 4; ++r){
      int batch = ((l >> 4) << 2) + r, unit = w * 64 + q * 16 + (l & 15);
      cstate[((size_t)blk * 16 + batch) * 256 + unit] = cst[q][r];
    }
}

// ---------------- layer-2 bwd single step ----------------
__global__ void k_h2b(const short* __restrict__ x2t, const float* __restrict__ Wi,
                      const float* __restrict__ bias, float* __restrict__ h2b){
  __shared__ float xr[512];
  int b = blockIdx.x, tid = threadIdx.x;
  for (int i = tid; i < 512; i += 256) xr[i] = bf2f(x2t[((size_t)1023 * 64 + b) * 512 + i]);
  __syncthreads();
  int u = tid;
  float s0 = bias[u], s2 = bias[512 + u], s3 = bias[768 + u];
  for (int k = 0; k < 512; ++k){
    float x = xr[k];
    const float* wr = Wi + (size_t)k * 1024;
    s0 += x * wr[u];
    s2 += x * wr[512 + u]; s3 += x * wr[768 + u];
  }
  float cc = sigm(s0) * tanh_(s2);          // c0 = 0 -> f-term drops
  float hh = sigm(s3) * tanh_(cc);
  h2b[(size_t)b * 256 + u] = hh;
}

// h2f (hstate2) is stored in A-layout blocks of 4096 shorts per cb
__global__ void k_logits(const short* __restrict__ h2f, const float* __restrict__ h2b,
                         const float* __restrict__ Wd, const float* __restrict__ bd,
                         float* __restrict__ out){
  int b = threadIdx.x;          // 64 threads
  int cb = b >> 4, bl = b & 15;
  float s = bd[0];
  for (int u = 0; u < 256; ++u){
    int kk = u >> 5, Lp = bl + 16 * ((u >> 3) & 3), j = u & 7;
    s += bf2f(h2f[(size_t)cb * 4096 + kk * 512 + Lp * 8 + j]) * Wd[u];
  }
  for (int k = 0; k < 256; ++k) s += h2b[(size_t)b * 256 + k] * Wd[256 + k];
  out[b] = sigm(s);
}

// ---------------- host ----------------
extern "C" void kernel_launch(void* const* d_in, const int* in_sizes, int n_in,
                              void* d_out, int out_size, void* d_ws, size_t ws_size,
                              hipStream_t stream)
{
  (void)in_sizes; (void)n_in; (void)out_size;
  const int*   tokens = (const int*)d_in[0];
  const float* embed  = (const float*)d_in[1];
  const float* fw1_Wi = (const float*)d_in[2];
  const float* fw1_Wh = (const float*)d_in[3];
  const float* fw1_b  = (const float*)d_in[4];
  const float* bw1_Wi = (const float*)d_in[5];
  const float* bw1_Wh = (const float*)d_in[6];
  const float* bw1_b  = (const float*)d_in[7];
  const float* fw2_Wi = (const float*)d_in[8];
  const float* fw2_Wh = (const float*)d_in[9];
  const float* fw2_b  = (const float*)d_in[10];
  const float* bw2_Wi = (const float*)d_in[11];
  const float* bw2_Wh = (const float*)d_in[12];
  const float* bw2_b  = (const float*)d_in[13];
  const float* Wd     = (const float*)d_in[14];
  const float* bd     = (const float*)d_in[15];
  float* out = (float*)d_out;

  auto total_for = [](int S)->size_t{
    size_t fixed = 33554432ull + 67108864ull
                 + 524288ull*2 + 1048576ull
                 + 524288ull*3
                 + 12288ull
                 + 131072ull + 65536ull
                 + 65536ull + 32768ull
                 + 65536ull + 65536ull;
    return fixed + 2ull * (size_t)S * 131072ull;
  };
  int S = 256;
  while (S > 32 && total_for(S) > ws_size) S >>= 1;
  int NC = 1024 / S;

  char* ws = (char*)d_ws;
  size_t o = 0;
  auto alloc = [&](size_t sz){ size_t r = o; o += (sz + 255) & ~(size_t)255; return r; };
  short* x1t    = (short*)(ws + alloc(64ull * 1024 * 256 * 2));   // 32MB
  short* x2t    = (short*)(ws + alloc(64ull * 1024 * 512 * 2));   // 64MB
  short* xwf    = (short*)(ws + alloc((size_t)S * 131072ull));
  short* xwb    = (short*)(ws + alloc((size_t)S * 131072ull));
  short* wipT1f = (short*)(ws + alloc(256ull * 1024 * 2));
  short* wipT1b = (short*)(ws + alloc(256ull * 1024 * 2));
  short* wipT2f = (short*)(ws + alloc(512ull * 1024 * 2));
  short* wht1f  = (short*)(ws + alloc(256ull * 1024 * 2));
  short* wht1b  = (short*)(ws + alloc(256ull * 1024 * 2));
  short* wht2f  = (short*)(ws + alloc(256ull * 1024 * 2));
  float* bp1f   = (float*)(ws + alloc(1024 * 4));
  float* bp1b   = (float*)(ws + alloc(1024 * 4));
  float* bp2f   = (float*)(ws + alloc(1024 * 4));
  float* cst1   = (float*)(ws + alloc(2ull * 64 * 256 * 4));
  short* hst1   = (short*)(ws + alloc(2ull * 64 * 256 * 2));
  float* cst2   = (float*)(ws + alloc(64ull * 256 * 4));
  short* hst2   = (short*)(ws + alloc(64ull * 256 * 2));
  float* h2b    = (float*)(ws + alloc(64ull * 256 * 4));

  const int LDS_RECUR = 151552 + 8192;  // 159744 B
  hipFuncSetAttribute((const void*)&k_recur<1>, hipFuncAttributeMaxDynamicSharedMemorySize, LDS_RECUR);
  hipFuncSetAttribute((const void*)&k_recur<0>, hipFuncAttributeMaxDynamicSharedMemorySize, LDS_RECUR);

  // weight prep
  k_prep_wipT<<<128, 256, 0, stream>>>(fw1_Wi, wipT1f, 256);
  k_prep_wipT<<<128, 256, 0, stream>>>(bw1_Wi, wipT1b, 256);
  k_prep_wipT<<<256, 256, 0, stream>>>(fw2_Wi, wipT2f, 512);
  k_prep_bias<<<4, 256, 0, stream>>>(fw1_b, bp1f);
  k_prep_bias<<<4, 256, 0, stream>>>(bw1_b, bp1b);
  k_prep_bias<<<4, 256, 0, stream>>>(fw2_b, bp2f);
  k_prep_wht<<<128, 256, 0, stream>>>(fw1_Wh, wht1f);
  k_prep_wht<<<128, 256, 0, stream>>>(bw1_Wh, wht1b);
  k_prep_wht<<<128, 256, 0, stream>>>(fw2_Wh, wht2f);

  // embedding gather
  k_gather<<<4096, 256, 0, stream>>>(tokens, embed, x1t);

  dim3 ggrid(S / 2, 8);

  // ---- layer 1, chunked over time ----
  for (int c = 0; c < NC; ++c){
    int t0 = c * S;
    const short* Af = x1t + (size_t)t0 * 64 * 256;
    const short* Ab = x1t + (size_t)(1024 - (c + 1) * S) * 64 * 256;
    k_gemm<256><<<ggrid, 256, 0, stream>>>(Af, wipT1f, bp1f, xwf);
    k_gemm<256><<<ggrid, 256, 0, stream>>>(Ab, wipT1b, bp1b, xwb);
    k_recur<1><<<8, 256, LDS_RECUR, stream>>>(xwf, xwb, wht1f, wht1b,
                                              x2t, cst1, hst1, t0, S, 1, c == 0);
  }

  // ---- layer 2 fwd, chunked ----
  for (int c = 0; c < NC; ++c){
    int t0 = c * S;
    const short* A2 = x2t + (size_t)t0 * 64 * 512;
    k_gemm<512><<<ggrid, 256, 0, stream>>>(A2, wipT2f, bp2f, xwf);
    k_recur<0><<<4, 256, LDS_RECUR, stream>>>(xwf, xwf, wht2f, wht2f,
                                              (short*)nullptr, cst2, hst2, t0, S, 0, c == 0);
  }

  // ---- layer 2 bwd = single step at t=1023 ----
  k_h2b<<<64, 256, 0, stream>>>(x2t, bw2_Wi, bw2_b, h2b);

  // ---- head ----
  k_logits<<<1, 64, 0, stream>>>(hst2, h2b, Wd, bd, out);
}

// Round 5
// 4752.710 us; speedup vs baseline: 1.8887x; 1.8887x over previous
//
#include <hip/hip_runtime.h>
#include <hip/hip_bf16.h>
#include <cstdint>
#include <cstddef>

typedef __attribute__((ext_vector_type(8))) short bf16x8;
typedef __attribute__((ext_vector_type(4))) short bf16x4;
typedef __attribute__((ext_vector_type(4))) float f32x4;
typedef unsigned long long u64;

#define LOG2E 1.442695041f

__device__ __forceinline__ float bf2f(short s){
  unsigned int u = ((unsigned int)(unsigned short)s) << 16;
  return __builtin_bit_cast(float, u);
}
__device__ __forceinline__ short f2bf(float f){
  unsigned int u = __builtin_bit_cast(unsigned int, f);
  unsigned int r = (u + 0x7fff + ((u >> 16) & 1)) >> 16;
  return (short)r;
}
__device__ __forceinline__ float sigm(float x){
  return __builtin_amdgcn_rcpf(1.f + __builtin_amdgcn_exp2f(-LOG2E * x));
}
__device__ __forceinline__ float tanh_(float x){
  return 1.f - 2.f * __builtin_amdgcn_rcpf(1.f + __builtin_amdgcn_exp2f(2.f * LOG2E * x));
}
__device__ __forceinline__ void wg_barrier(){
  asm volatile("s_waitcnt lgkmcnt(0)" ::: "memory");
  __builtin_amdgcn_s_barrier();
  asm volatile("" ::: "memory");
}
// 8-wave permutation: np = w*128 + gate*32 + ul  ->  orig = gate*256 + w*32 + ul
__device__ __forceinline__ int orig_col8(int np){
  int w = np >> 7, rem = np & 127, gate = rem >> 5, ul = rem & 31;
  return gate * 256 + w * 32 + ul;
}
__device__ __forceinline__ char f2fp8(float x){
  int pk = __builtin_amdgcn_cvt_pk_fp8_f32(x, x, 0, false);
  return (char)(pk & 0xff);
}

// ---------------- prep kernels ----------------
__global__ void k_prep_wipT(const float* __restrict__ Wi, short* __restrict__ outT, int K){
  int idx = blockIdx.x * 256 + threadIdx.x;      // over 1024*K/8
  int kv = K >> 3;
  int np = idx / kv, k0 = (idx % kv) * 8;
  int oc = orig_col8(np);
  bf16x8 v;
  #pragma unroll
  for (int j = 0; j < 8; ++j) v[j] = f2bf(Wi[(size_t)(k0 + j) * 1024 + oc]);
  *(bf16x8*)(outT + (size_t)np * K + k0) = v;
}

__global__ void k_prep_bias(const float* __restrict__ b, float* __restrict__ bp){
  int np = blockIdx.x * 256 + threadIdx.x;
  bp[np] = b[orig_col8(np)];
}

// Wh [256,1024] f32 -> fp8 B-frag-tiled: w8[(ng*8+kk)*64+l] = 8 bytes, byte j = fp8(Wh[kk*32+(l>>4)*8+j][orig8(ng*16+(l&15))])
__global__ void k_prep_wht8(const float* __restrict__ Wh, u64* __restrict__ w8){
  int idx = blockIdx.x * 256 + threadIdx.x;      // 32768
  int l = idx & 63, fk = idx >> 6, kk = fk & 7, ng = fk >> 3;
  int oc = orig_col8(ng * 16 + (l & 15));
  int kbase = kk * 32 + ((l >> 4) << 3);
  u64 v = 0;
  #pragma unroll
  for (int j = 0; j < 8; ++j){
    unsigned int b = (unsigned char)f2fp8(Wh[(size_t)(kbase + j) * 1024 + oc]);
    v |= ((u64)b) << (8 * j);
  }
  w8[idx] = v;
}

// embedding gather: x1t[(t*64+b)][k] = bf16(embed[tokens[b][t]][k])
__global__ void k_gather(const int* __restrict__ tokens, const float* __restrict__ embed,
                         short* __restrict__ x1t){
  int v = blockIdx.x * 256 + threadIdx.x;
  const int total = 64 * 1024 * 256 / 4;
  for (; v < total; v += gridDim.x * 256){
    int e = v * 4;
    int row = e >> 8, k = e & 255;
    int t = row >> 6, b = row & 63;
    int tok = tokens[b * 1024 + t];
    f32x4 f = *(const f32x4*)(embed + (size_t)tok * 256 + k);
    bf16x4 o4;
    #pragma unroll
    for (int j = 0; j < 4; ++j) o4[j] = f2bf(f[j]);
    *(bf16x4*)(x1t + e) = o4;
  }
}

// ---------------- input-projection GEMM (chunk of timesteps) ----------------
// A [S*64, K] bf16 (rows lt*64+b), BT [1024][K] bf16 (permuted cols), bias f32[1024]
// out xw bf16 frag-tiled: ((lt*4+cb)*64 + ng)*256 + l*4 + r
template<int K>
__global__ __launch_bounds__(256)
void k_gemm(const short* __restrict__ A, const short* __restrict__ BT,
            const float* __restrict__ bias, short* __restrict__ xw){
  __shared__ short ldsA[128 * 72];
  __shared__ short ldsB[128 * 72];
  int tid = threadIdx.x;
  int l = tid & 63, wid = tid >> 6, wm = wid >> 1, wn = wid & 1;
  int M0 = blockIdx.x * 128, N0 = blockIdx.y * 128;
  f32x4 acc[4][4] = {};
  for (int kt = 0; kt < K / 64; ++kt){
    __syncthreads();
    for (int i = tid; i < 1024; i += 256){
      int row = i >> 3, seg = i & 7;
      *(bf16x8*)&ldsA[row * 72 + seg * 8] = *(const bf16x8*)&A[(size_t)(M0 + row) * K + kt * 64 + seg * 8];
      *(bf16x8*)&ldsB[row * 72 + seg * 8] = *(const bf16x8*)&BT[(size_t)(N0 + row) * K + kt * 64 + seg * 8];
    }
    __syncthreads();
    #pragma unroll
    for (int kk = 0; kk < 2; ++kk){
      int koff = kk * 32 + ((l >> 4) << 3);
      bf16x8 af[4], bfm[4];
      #pragma unroll
      for (int mt = 0; mt < 4; ++mt) af[mt] = *(const bf16x8*)&ldsA[(wm * 64 + mt * 16 + (l & 15)) * 72 + koff];
      #pragma unroll
      for (int nt = 0; nt < 4; ++nt) bfm[nt] = *(const bf16x8*)&ldsB[(wn * 64 + nt * 16 + (l & 15)) * 72 + koff];
      #pragma unroll
      for (int mt = 0; mt < 4; ++mt)
        #pragma unroll
        for (int nt = 0; nt < 4; ++nt)
          acc[mt][nt] = __builtin_amdgcn_mfma_f32_16x16x32_bf16(af[mt], bfm[nt], acc[mt][nt], 0, 0, 0);
    }
  }
  int t = blockIdx.x * 2 + wm;   // chunk-local t
  #pragma unroll
  for (int mt = 0; mt < 4; ++mt){
    #pragma unroll
    for (int nt = 0; nt < 4; ++nt){
      int ng = (N0 >> 4) + wn * 4 + nt;
      float bs = bias[ng * 16 + (l & 15)];
      bf16x4 ov;
      #pragma unroll
      for (int r = 0; r < 4; ++r) ov[r] = f2bf(acc[mt][nt][r] + bs);
      *(bf16x4*)&xw[((size_t)(t * 4 + mt) * 64 + ng) * 256 + l * 4] = ov;
    }
  }
}

// ---------------- recurrence (8 waves, fp8 Wh all in regs, 2 waves/SIMD) ----------------
// WG = 512 threads = 8 waves; wave w owns permuted gate-cols [w*128, w*128+128) = units w*32..w*32+32 (all 4 gates).
// h in LDS as fp8 A-fragments, double-buffered (2 x 4KB): byte = buf*4096 + kk*512 + L*8 + j,
//   representing h[batch = L&15][unit = kk*32 + (L>>4)*8 + j].
template<int WRITE_SEQ>
__global__ __launch_bounds__(512, 2)
void k_recur8(const short* __restrict__ xw_f, const short* __restrict__ xw_b,
              const u64* __restrict__ w8_f, const u64* __restrict__ w8_b,
              short* __restrict__ outp, float* __restrict__ cstate, u64* __restrict__ hstate,
              int t0, int S, int two_dirs, int first)
{
  __shared__ char ldsH[8192];
  int g = blockIdx.x;
  int d  = two_dirs ? (g >> 2) : 0;
  int cb = two_dirs ? (g & 3) : g;
  int blk = g;
  const short* xw = d ? xw_b : xw_f;
  const u64*  w8  = d ? w8_b : w8_f;
  int tid = threadIdx.x, w = tid >> 6, l = tid & 63;

  // B fragments (fp8) fully in registers: 64 x 8B = 128 VGPRs
  u64 Breg[64];
  #pragma unroll
  for (int n = 0; n < 8; ++n)
    #pragma unroll
    for (int kk = 0; kk < 8; ++kk)
      Breg[n * 8 + kk] = w8[((size_t)(w * 8 + n) * 8 + kk) * 64 + l];

  // h/c state init
  f32x4 cst[2];
  if (first){
    *(u64*)(ldsH + tid * 8) = 0ull;                 // zero buf0 (4KB)
    cst[0] = f32x4{0.f,0.f,0.f,0.f};
    cst[1] = f32x4{0.f,0.f,0.f,0.f};
  } else {
    *(u64*)(ldsH + tid * 8) = hstate[(size_t)blk * 512 + tid];
    #pragma unroll
    for (int uh = 0; uh < 2; ++uh)
      #pragma unroll
      for (int r = 0; r < 4; ++r){
        int batch = ((l >> 4) << 2) + r, unit = w * 32 + uh * 16 + (l & 15);
        cst[uh][r] = cstate[((size_t)blk * 16 + batch) * 256 + unit];
      }
  }
  __syncthreads();

  // x stream
  long xwStep = (d ? -1l : 1l) * 4 * 64 * 256;
  const short* xwCur = xw + ((size_t)((d ? (S - 1) : 0) * 4 + cb) * 64) * 256;
  bf16x4 px[8];
  #pragma unroll
  for (int n = 0; n < 8; ++n)
    px[n] = *(const bf16x4*)&xwCur[((w * 8 + n) * 64 + l) * 4];

  // seq-store base (layer1): row = t*64 + cb*16 + (l>>4)*4 (+r), col = d*256 + w*32 + uh*16 + (l&15)
  char* seqB = nullptr;
  long seqStepB = (d ? -1l : 1l) * 64 * 512 * 2;
  if (WRITE_SEQ)
    seqB = (char*)(outp + ((long)(d ? (1023 - t0) : t0) * 64 + cb * 16 + ((l >> 4) << 2)) * 512
                        + d * 256 + w * 32 + (l & 15));

  // h-write base: byte = bufX*4096 + w*512 + ((l&15)>>3)*128 + (l>>4)*32 + (l&7); offsets uh*256 + r*8
  int hwOff = w * 512 + (((l & 15) >> 3) << 7) + ((l >> 4) << 5) + (l & 7);

  int p = 0;
  #pragma unroll 1
  for (int s = 0; s < S; ++s){
    const short* xwNext = (s + 1 < S) ? (xwCur + xwStep) : xwCur;

    const char* aB = ldsH + p * 4096 + l * 8;
    long af[8];
    #pragma unroll
    for (int kk = 0; kk < 8; ++kk) af[kk] = *(const long*)(aB + kk * 512);

    f32x4 acc[8];
    #pragma unroll
    for (int n = 0; n < 8; ++n)
      #pragma unroll
      for (int r = 0; r < 4; ++r) acc[n][r] = bf2f(px[n][r]);

    // refill for next step (full-step latency window)
    #pragma unroll
    for (int n = 0; n < 8; ++n)
      px[n] = *(const bf16x4*)&xwNext[((w * 8 + n) * 64 + l) * 4];

    #pragma unroll
    for (int kk = 0; kk < 8; ++kk)
      #pragma unroll
      for (int n = 0; n < 8; ++n)
        acc[n] = __builtin_amdgcn_mfma_f32_16x16x32_fp8_fp8(af[kk], (long)Breg[n * 8 + kk], acc[n], 0, 0, 0);

    // gates: tiles (uh, 2+uh, 4+uh, 6+uh) = i,f,g,o for unit w*32 + uh*16 + (l&15), batch (l>>4)*4+r
    char* hw = ldsH + (p ^ 1) * 4096 + hwOff;
    #pragma unroll
    for (int uh = 0; uh < 2; ++uh){
      #pragma unroll
      for (int r = 0; r < 4; ++r){
        float ii = sigm(acc[uh][r]);
        float ff = sigm(acc[2 + uh][r]);
        float gg = tanh_(acc[4 + uh][r]);
        float oo = sigm(acc[6 + uh][r]);
        float cc = ff * cst[uh][r] + ii * gg;
        cst[uh][r] = cc;
        float hh = oo * tanh_(cc);
        *(char*)(hw + uh * 256 + r * 8) = f2fp8(hh);
        if (WRITE_SEQ){
          *(short*)(seqB + uh * 32 + r * 1024) = f2bf(hh);
        } else if (s == S - 1){
          outp[((size_t)cb * 16 + ((l >> 4) << 2) + r) * 256 + w * 32 + uh * 16 + (l & 15)] = f2bf(hh);
        }
      }
    }
    wg_barrier();   // single barrier per step (h double-buffered)
    p ^= 1;
    if (WRITE_SEQ) seqB += seqStepB;
    xwCur = xwNext;
  }

  // save state
  hstate[(size_t)blk * 512 + tid] = *(const u64*)(ldsH + p * 4096 + tid * 8);
  #pragma unroll
  for (int uh = 0; uh < 2; ++uh)
    #pragma unroll
    for (int r = 0; r < 4; ++r){
      int batch = ((l >> 4) << 2) + r, unit = w * 32 + uh * 16 + (l & 15);
      cstate[((size_t)blk * 16 + batch) * 256 + unit] = cst[uh][r];
    }
}

// ---------------- layer-2 bwd single step ----------------
__global__ void k_h2b(const short* __restrict__ x2t, const float* __restrict__ Wi,
                      const float* __restrict__ bias, float* __restrict__ h2b){
  __shared__ float xr[512];
  int b = blockIdx.x, tid = threadIdx.x;
  for (int i = tid; i < 512; i += 256) xr[i] = bf2f(x2t[((size_t)1023 * 64 + b) * 512 + i]);
  __syncthreads();
  int u = tid;
  float s0 = bias[u], s2 = bias[512 + u], s3 = bias[768 + u];
  for (int k = 0; k < 512; ++k){
    float x = xr[k];
    const float* wr = Wi + (size_t)k * 1024;
    s0 += x * wr[u];
    s2 += x * wr[512 + u]; s3 += x * wr[768 + u];
  }
  float cc = sigm(s0) * tanh_(s2);          // c0 = 0 -> f-term drops
  float hh = sigm(s3) * tanh_(cc);
  h2b[(size_t)b * 256 + u] = hh;
}

// h2f now plain [b][u] bf16
__global__ void k_logits(const short* __restrict__ h2f, const float* __restrict__ h2b,
                         const float* __restrict__ Wd, const float* __restrict__ bd,
                         float* __restrict__ out){
  int b = threadIdx.x;          // 64 threads
  float s = bd[0];
  for (int k = 0; k < 256; ++k) s += bf2f(h2f[b * 256 + k]) * Wd[k];
  for (int k = 0; k < 256; ++k) s += h2b[(size_t)b * 256 + k] * Wd[256 + k];
  out[b] = sigm(s);
}

// ---------------- host ----------------
extern "C" void kernel_launch(void* const* d_in, const int* in_sizes, int n_in,
                              void* d_out, int out_size, void* d_ws, size_t ws_size,
                              hipStream_t stream)
{
  (void)in_sizes; (void)n_in; (void)out_size;
  const int*   tokens = (const int*)d_in[0];
  const float* embed  = (const float*)d_in[1];
  const float* fw1_Wi = (const float*)d_in[2];
  const float* fw1_Wh = (const float*)d_in[3];
  const float* fw1_b  = (const float*)d_in[4];
  const float* bw1_Wi = (const float*)d_in[5];
  const float* bw1_Wh = (const float*)d_in[6];
  const float* bw1_b  = (const float*)d_in[7];
  const float* fw2_Wi = (const float*)d_in[8];
  const float* fw2_Wh = (const float*)d_in[9];
  const float* fw2_b  = (const float*)d_in[10];
  const float* bw2_Wi = (const float*)d_in[11];
  const float* bw2_Wh = (const float*)d_in[12];
  const float* bw2_b  = (const float*)d_in[13];
  const float* Wd     = (const float*)d_in[14];
  const float* bd     = (const float*)d_in[15];
  float* out = (float*)d_out;

  auto total_for = [](int S)->size_t{
    size_t fixed = 33554432ull + 67108864ull          // x1t, x2t
                 + 524288ull*2 + 1048576ull           // wipT
                 + 262144ull*3                        // wht8 x3
                 + 12288ull                           // biases
                 + 131072ull + 32768ull               // cst1, hstf8_1
                 + 65536ull + 16384ull                // cst2, hstf8_2
                 + 32768ull + 65536ull + 65536ull;    // hst2bf, h2b, slack
    return fixed + 2ull * (size_t)S * 131072ull;
  };
  int S = 256;
  while (S > 32 && total_for(S) > ws_size) S >>= 1;
  int NC = 1024 / S;

  char* ws = (char*)d_ws;
  size_t o = 0;
  auto alloc = [&](size_t sz){ size_t r = o; o += (sz + 255) & ~(size_t)255; return r; };
  short* x1t    = (short*)(ws + alloc(64ull * 1024 * 256 * 2));   // 32MB
  short* x2t    = (short*)(ws + alloc(64ull * 1024 * 512 * 2));   // 64MB
  short* xwf    = (short*)(ws + alloc((size_t)S * 131072ull));
  short* xwb    = (short*)(ws + alloc((size_t)S * 131072ull));
  short* wipT1f = (short*)(ws + alloc(256ull * 1024 * 2));
  short* wipT1b = (short*)(ws + alloc(256ull * 1024 * 2));
  short* wipT2f = (short*)(ws + alloc(512ull * 1024 * 2));
  u64*   w81f   = (u64*)(ws + alloc(262144ull));
  u64*   w81b   = (u64*)(ws + alloc(262144ull));
  u64*   w82f   = (u64*)(ws + alloc(262144ull));
  float* bp1f   = (float*)(ws + alloc(1024 * 4));
  float* bp1b   = (float*)(ws + alloc(1024 * 4));
  float* bp2f   = (float*)(ws + alloc(1024 * 4));
  float* cst1   = (float*)(ws + alloc(2ull * 64 * 256 * 4));      // 8 blks x 16 x 256
  u64*   hstf81 = (u64*)(ws + alloc(8ull * 512 * 8));
  float* cst2   = (float*)(ws + alloc(64ull * 256 * 4));          // 4 blks x 16 x 256
  u64*   hstf82 = (u64*)(ws + alloc(4ull * 512 * 8));
  short* hst2bf = (short*)(ws + alloc(64ull * 256 * 2));          // final layer-2 fwd h, [b][u] bf16
  float* h2b    = (float*)(ws + alloc(64ull * 256 * 4));

  // weight prep
  k_prep_wipT<<<128, 256, 0, stream>>>(fw1_Wi, wipT1f, 256);
  k_prep_wipT<<<128, 256, 0, stream>>>(bw1_Wi, wipT1b, 256);
  k_prep_wipT<<<256, 256, 0, stream>>>(fw2_Wi, wipT2f, 512);
  k_prep_bias<<<4, 256, 0, stream>>>(fw1_b, bp1f);
  k_prep_bias<<<4, 256, 0, stream>>>(bw1_b, bp1b);
  k_prep_bias<<<4, 256, 0, stream>>>(fw2_b, bp2f);
  k_prep_wht8<<<128, 256, 0, stream>>>(fw1_Wh, w81f);
  k_prep_wht8<<<128, 256, 0, stream>>>(bw1_Wh, w81b);
  k_prep_wht8<<<128, 256, 0, stream>>>(fw2_Wh, w82f);

  // embedding gather
  k_gather<<<4096, 256, 0, stream>>>(tokens, embed, x1t);

  dim3 ggrid(S / 2, 8);

  // ---- layer 1, chunked over time ----
  for (int c = 0; c < NC; ++c){
    int t0 = c * S;
    const short* Af = x1t + (size_t)t0 * 64 * 256;
    const short* Ab = x1t + (size_t)(1024 - (c + 1) * S) * 64 * 256;
    k_gemm<256><<<ggrid, 256, 0, stream>>>(Af, wipT1f, bp1f, xwf);
    k_gemm<256><<<ggrid, 256, 0, stream>>>(Ab, wipT1b, bp1b, xwb);
    k_recur8<1><<<8, 512, 0, stream>>>(xwf, xwb, w81f, w81b,
                                       x2t, cst1, hstf81, t0, S, 1, c == 0);
  }

  // ---- layer 2 fwd, chunked ----
  for (int c = 0; c < NC; ++c){
    int t0 = c * S;
    const short* A2 = x2t + (size_t)t0 * 64 * 512;
    k_gemm<512><<<ggrid, 256, 0, stream>>>(A2, wipT2f, bp2f, xwf);
    k_recur8<0><<<4, 512, 0, stream>>>(xwf, xwf, w82f, w82f,
                                       hst2bf, cst2, hstf82, t0, S, 0, c == 0);
  }

  // ---- layer 2 bwd = single step at t=1023 ----
  k_h2b<<<64, 256, 0, stream>>>(x2t, bw2_Wi, bw2_b, h2b);

  // ---- head ----
  k_logits<<<1, 64, 0, stream>>>(hst2bf, h2b, Wd, bd, out);
}

// Round 6
// 4283.702 us; speedup vs baseline: 2.0955x; 1.1095x over previous
//
#include <hip/hip_runtime.h>
#include <hip/hip_bf16.h>
#include <cstdint>
#include <cstddef>

typedef __attribute__((ext_vector_type(8))) short bf16x8;
typedef __attribute__((ext_vector_type(4))) short bf16x4;
typedef __attribute__((ext_vector_type(4))) float f32x4;
typedef __attribute__((ext_vector_type(4))) int   i32x4;
typedef __attribute__((ext_vector_type(8))) int   i32x8;
typedef unsigned long long u64;

#define LOG2E 1.442695041f

__device__ __forceinline__ float bf2f(short s){
  unsigned int u = ((unsigned int)(unsigned short)s) << 16;
  return __builtin_bit_cast(float, u);
}
__device__ __forceinline__ short f2bf(float f){
  return __builtin_bit_cast(short, __float2bfloat16(f));   // HW RNE cvt
}
__device__ __forceinline__ float sigm(float x){
  return __builtin_amdgcn_rcpf(1.f + __builtin_amdgcn_exp2f(-LOG2E * x));
}
__device__ __forceinline__ float tanh_(float x){
  return 1.f - 2.f * __builtin_amdgcn_rcpf(1.f + __builtin_amdgcn_exp2f(2.f * LOG2E * x));
}
__device__ __forceinline__ void wg_barrier(){
  asm volatile("s_waitcnt lgkmcnt(0)" ::: "memory");
  __builtin_amdgcn_s_barrier();
  asm volatile("" ::: "memory");
}
// 8-wave permutation: np = w*128 + gate*32 + ul  ->  orig = gate*256 + w*32 + ul
__device__ __forceinline__ int orig_col8(int np){
  int w = np >> 7, rem = np & 127, gate = rem >> 5, ul = rem & 31;
  return gate * 256 + w * 32 + ul;
}
__device__ __forceinline__ char f2fp8(float x){
  int pk = __builtin_amdgcn_cvt_pk_fp8_f32(x, x, 0, false);
  return (char)(pk & 0xff);
}

// ---------------- prep kernels ----------------
__global__ void k_prep_wipT(const float* __restrict__ Wi, short* __restrict__ outT, int K){
  int idx = blockIdx.x * 256 + threadIdx.x;      // over 1024*K/8
  int kv = K >> 3;
  int np = idx / kv, k0 = (idx % kv) * 8;
  int oc = orig_col8(np);
  bf16x8 v;
  #pragma unroll
  for (int j = 0; j < 8; ++j) v[j] = f2bf(Wi[(size_t)(k0 + j) * 1024 + oc]);
  *(bf16x8*)(outT + (size_t)np * K + k0) = v;
}

__global__ void k_prep_bias(const float* __restrict__ b, float* __restrict__ bp){
  int np = blockIdx.x * 256 + threadIdx.x;
  bp[np] = b[orig_col8(np)];
}

// Wh [256,1024] f32 -> fp8 B-frags for 16x16x128: idx = ((wn*2)+kki)*64 + l, 32 bytes:
// byte (qq*8+j) = fp8(Wh[kki*128 + (l>>4)*32 + qq*8 + j][orig8(wn*16 + (l&15))])
__global__ void k_prep_wht8(const float* __restrict__ Wh, u64* __restrict__ w8){
  int idx = blockIdx.x * 256 + threadIdx.x;      // 8192
  int l = idx & 63, fk = idx >> 6;               // fk = wn*2 + kki
  int kki = fk & 1, wn = fk >> 1;
  int oc = orig_col8(wn * 16 + (l & 15));
  int kbase = kki * 128 + ((l >> 4) << 5);
  u64* dst = w8 + (size_t)idx * 4;
  #pragma unroll
  for (int qq = 0; qq < 4; ++qq){
    u64 x = 0;
    #pragma unroll
    for (int j = 0; j < 8; ++j){
      unsigned int b = (unsigned char)f2fp8(Wh[(size_t)(kbase + qq * 8 + j) * 1024 + oc]);
      x |= ((u64)b) << (8 * j);
    }
    dst[qq] = x;
  }
}

// embedding gather: x1t[(t*64+b)][k] = bf16(embed[tokens[b][t]][k])
__global__ void k_gather(const int* __restrict__ tokens, const float* __restrict__ embed,
                         short* __restrict__ x1t){
  int v = blockIdx.x * 256 + threadIdx.x;
  const int total = 64 * 1024 * 256 / 4;
  for (; v < total; v += gridDim.x * 256){
    int e = v * 4;
    int row = e >> 8, k = e & 255;
    int t = row >> 6, b = row & 63;
    int tok = tokens[b * 1024 + t];
    f32x4 f = *(const f32x4*)(embed + (size_t)tok * 256 + k);
    bf16x4 o4;
    #pragma unroll
    for (int j = 0; j < 4; ++j) o4[j] = f2bf(f[j]);
    *(bf16x4*)(x1t + e) = o4;
  }
}

// ---------------- input-projection GEMM (chunk of timesteps), f32 output ----------------
template<int K>
__global__ __launch_bounds__(256)
void k_gemm(const short* __restrict__ A, const short* __restrict__ BT,
            const float* __restrict__ bias, float* __restrict__ xw){
  __shared__ short ldsA[128 * 72];
  __shared__ short ldsB[128 * 72];
  int tid = threadIdx.x;
  int l = tid & 63, wid = tid >> 6, wm = wid >> 1, wn = wid & 1;
  int M0 = blockIdx.x * 128, N0 = blockIdx.y * 128;
  f32x4 acc[4][4] = {};
  for (int kt = 0; kt < K / 64; ++kt){
    __syncthreads();
    for (int i = tid; i < 1024; i += 256){
      int row = i >> 3, seg = i & 7;
      *(bf16x8*)&ldsA[row * 72 + seg * 8] = *(const bf16x8*)&A[(size_t)(M0 + row) * K + kt * 64 + seg * 8];
      *(bf16x8*)&ldsB[row * 72 + seg * 8] = *(const bf16x8*)&BT[(size_t)(N0 + row) * K + kt * 64 + seg * 8];
    }
    __syncthreads();
    #pragma unroll
    for (int kk = 0; kk < 2; ++kk){
      int koff = kk * 32 + ((l >> 4) << 3);
      bf16x8 af[4], bfm[4];
      #pragma unroll
      for (int mt = 0; mt < 4; ++mt) af[mt] = *(const bf16x8*)&ldsA[(wm * 64 + mt * 16 + (l & 15)) * 72 + koff];
      #pragma unroll
      for (int nt = 0; nt < 4; ++nt) bfm[nt] = *(const bf16x8*)&ldsB[(wn * 64 + nt * 16 + (l & 15)) * 72 + koff];
      #pragma unroll
      for (int mt = 0; mt < 4; ++mt)
        #pragma unroll
        for (int nt = 0; nt < 4; ++nt)
          acc[mt][nt] = __builtin_amdgcn_mfma_f32_16x16x32_bf16(af[mt], bfm[nt], acc[mt][nt], 0, 0, 0);
    }
  }
  int t = blockIdx.x * 2 + wm;   // chunk-local t
  #pragma unroll
  for (int mt = 0; mt < 4; ++mt){
    #pragma unroll
    for (int nt = 0; nt < 4; ++nt){
      int ng = (N0 >> 4) + wn * 4 + nt;
      float bs = bias[ng * 16 + (l & 15)];
      f32x4 ov;
      #pragma unroll
      for (int r = 0; r < 4; ++r) ov[r] = acc[mt][nt][r] + bs;
      *(f32x4*)&xw[((size_t)(t * 4 + mt) * 64 + ng) * 256 + l * 4] = ov;
    }
  }
}

// ---------------- recurrence (8 waves, MX-fp8 K=128 MFMA, 2 waves/SIMD) ----------------
// h in LDS as fp8 K=128 A-fragments, double-buffered:
//   byte = buf*6144 + kblk*768 + batch*48 + (k&31),  kblk = k>>5  (48B stride: bank-spread)
template<int WRITE_SEQ>
__global__ __launch_bounds__(512, 2)
void k_recur8(const float* __restrict__ xw_f, const float* __restrict__ xw_b,
              const u64* __restrict__ w8_f, const u64* __restrict__ w8_b,
              short* __restrict__ outp, float* __restrict__ cstate, char* __restrict__ hstate,
              int t0, int S, int two_dirs, int first)
{
  __shared__ char ldsH[12288];
  int g = blockIdx.x;
  int d  = two_dirs ? (g >> 2) : 0;
  int cb = two_dirs ? (g & 3) : g;
  int blk = g;
  const float* xw = d ? xw_b : xw_f;
  const u64*  w8  = d ? w8_b : w8_f;
  int tid = threadIdx.x, w = tid >> 6, l = tid & 63;

  // B fragments (fp8, K=128) fully in registers: 16 x 32B = 128 VGPRs
  i32x8 Breg[16];
  #pragma unroll
  for (int n = 0; n < 8; ++n)
    #pragma unroll
    for (int kki = 0; kki < 2; ++kki){
      const i32x4* bp = (const i32x4*)(w8 + ((size_t)((w * 8 + n) * 2 + kki) * 64 + l) * 4);
      Breg[n * 2 + kki] = __builtin_shufflevector(bp[0], bp[1], 0,1,2,3,4,5,6,7);
    }

  // h/c state init
  f32x4 cst[2];
  if (first){
    if (tid < 384) *(i32x4*)(ldsH + tid * 16) = i32x4{0,0,0,0};
    cst[0] = f32x4{0.f,0.f,0.f,0.f};
    cst[1] = f32x4{0.f,0.f,0.f,0.f};
  } else {
    const char* hsrc = hstate + (size_t)blk * 6144;
    if (tid < 384) *(i32x4*)(ldsH + tid * 16) = *(const i32x4*)(hsrc + tid * 16);
    #pragma unroll
    for (int uh = 0; uh < 2; ++uh)
      #pragma unroll
      for (int r = 0; r < 4; ++r){
        int batch = ((l >> 4) << 2) + r, unit = w * 32 + uh * 16 + (l & 15);
        cst[uh][r] = cstate[((size_t)blk * 16 + batch) * 256 + unit];
      }
  }
  __syncthreads();

  // x stream (f32, frag layout)
  long xwStep = (d ? -1l : 1l) * 4 * 64 * 256;
  const float* xwCur = xw + ((size_t)((d ? (S - 1) : 0) * 4 + cb) * 64) * 256;
  f32x4 px[8];
  #pragma unroll
  for (int n = 0; n < 8; ++n)
    px[n] = *(const f32x4*)&xwCur[((w * 8 + n) * 64 + l) * 4];

  // seq-store base (layer1): row = t*64 + cb*16 + (l>>4)*4 (+r), col = d*256 + w*32 + uh*16 + (l&15)
  char* seqB = nullptr;
  long seqStepB = (d ? -1l : 1l) * 64 * 512 * 2;
  if (WRITE_SEQ)
    seqB = (char*)(outp + ((long)(d ? (1023 - t0) : t0) * 64 + cb * 16 + ((l >> 4) << 2)) * 512
                        + d * 256 + w * 32 + (l & 15));

  // per-thread LDS addresses
  const int aOff = (l & 15) * 48 + ((l >> 4) * 768);      // read base (within buf)
  const int hOff = w * 768 + ((l >> 4) << 2) * 48 + (l & 15);  // write base (+ r*48 + uh*16)

  int p = 0;
  #pragma unroll 1
  for (int s = 0; s < S; ++s){
    const float* xwNext = (s + 1 < S) ? (xwCur + xwStep) : xwCur;

    const char* aB = ldsH + p * 6144 + aOff;
    i32x4 a0 = *(const i32x4*)(aB);
    i32x4 a1 = *(const i32x4*)(aB + 16);
    i32x4 a2 = *(const i32x4*)(aB + 3072);
    i32x4 a3 = *(const i32x4*)(aB + 3088);
    i32x8 af0 = __builtin_shufflevector(a0, a1, 0,1,2,3,4,5,6,7);
    i32x8 af1 = __builtin_shufflevector(a2, a3, 0,1,2,3,4,5,6,7);

    f32x4 acc[8];
    acc[0] = px[0]; acc[2] = px[2]; acc[4] = px[4]; acc[6] = px[6];
    // MFMA block A: tiles 0,2,4,6 (i,f,g,o of uh=0)
    #pragma unroll
    for (int n = 0; n < 8; n += 2){
      acc[n] = __builtin_amdgcn_mfma_scale_f32_16x16x128_f8f6f4(
                 af0, Breg[n * 2 + 0], acc[n], 0, 0, 0, 0x7f7f7f7f, 0, 0x7f7f7f7f);
      acc[n] = __builtin_amdgcn_mfma_scale_f32_16x16x128_f8f6f4(
                 af1, Breg[n * 2 + 1], acc[n], 0, 0, 0, 0x7f7f7f7f, 0, 0x7f7f7f7f);
    }
    acc[1] = px[1]; acc[3] = px[3]; acc[5] = px[5]; acc[7] = px[7];
    // refill for next step (full-step latency window)
    #pragma unroll
    for (int n = 0; n < 8; ++n)
      px[n] = *(const f32x4*)&xwNext[((w * 8 + n) * 64 + l) * 4];
    // MFMA block B: tiles 1,3,5,7 (uh=1)
    #pragma unroll
    for (int n = 1; n < 8; n += 2){
      acc[n] = __builtin_amdgcn_mfma_scale_f32_16x16x128_f8f6f4(
                 af0, Breg[n * 2 + 0], acc[n], 0, 0, 0, 0x7f7f7f7f, 0, 0x7f7f7f7f);
      acc[n] = __builtin_amdgcn_mfma_scale_f32_16x16x128_f8f6f4(
                 af1, Breg[n * 2 + 1], acc[n], 0, 0, 0, 0x7f7f7f7f, 0, 0x7f7f7f7f);
    }

    // gates per uh (uh=0 can overlap MFMA block B in the scheduler)
    char* hw = ldsH + (p ^ 1) * 6144 + hOff;
    #pragma unroll
    for (int uh = 0; uh < 2; ++uh){
      #pragma unroll
      for (int r = 0; r < 4; ++r){
        float ii = sigm(acc[0 + uh][r]);
        float ff = sigm(acc[2 + uh][r]);
        float gg = tanh_(acc[4 + uh][r]);
        float oo = sigm(acc[6 + uh][r]);
        float cc = ff * cst[uh][r] + ii * gg;
        cst[uh][r] = cc;
        float hh = oo * tanh_(cc);
        *(char*)(hw + r * 48 + uh * 16) = f2fp8(hh);
        if (WRITE_SEQ){
          *(short*)(seqB + uh * 32 + r * 1024) = f2bf(hh);
        } else if (s == S - 1){
          outp[((size_t)cb * 16 + ((l >> 4) << 2) + r) * 256 + w * 32 + uh * 16 + (l & 15)] = f2bf(hh);
        }
      }
    }
    wg_barrier();   // single barrier per step (h double-buffered)
    p ^= 1;
    if (WRITE_SEQ) seqB += seqStepB;
    xwCur = xwNext;
  }

  // save state
  {
    char* hdst = hstate + (size_t)blk * 6144;
    if (tid < 384) *(i32x4*)(hdst + tid * 16) = *(const i32x4*)(ldsH + p * 6144 + tid * 16);
  }
  #pragma unroll
  for (int uh = 0; uh < 2; ++uh)
    #pragma unroll
    for (int r = 0; r < 4; ++r){
      int batch = ((l >> 4) << 2) + r, unit = w * 32 + uh * 16 + (l & 15);
      cstate[((size_t)blk * 16 + batch) * 256 + unit] = cst[uh][r];
    }
}

// ---------------- layer-2 bwd single step ----------------
__global__ void k_h2b(const short* __restrict__ x2t, const float* __restrict__ Wi,
                      const float* __restrict__ bias, float* __restrict__ h2b){
  __shared__ float xr[512];
  int b = blockIdx.x, tid = threadIdx.x;
  for (int i = tid; i < 512; i += 256) xr[i] = bf2f(x2t[((size_t)1023 * 64 + b) * 512 + i]);
  __syncthreads();
  int u = tid;
  float s0 = bias[u], s2 = bias[512 + u], s3 = bias[768 + u];
  for (int k = 0; k < 512; ++k){
    float x = xr[k];
    const float* wr = Wi + (size_t)k * 1024;
    s0 += x * wr[u];
    s2 += x * wr[512 + u]; s3 += x * wr[768 + u];
  }
  float cc = sigm(s0) * tanh_(s2);          // c0 = 0 -> f-term drops
  float hh = sigm(s3) * tanh_(cc);
  h2b[(size_t)b * 256 + u] = hh;
}

// h2f plain [b][u] bf16
__global__ void k_logits(const short* __restrict__ h2f, const float* __restrict__ h2b,
                         const float* __restrict__ Wd, const float* __restrict__ bd,
                         float* __restrict__ out){
  int b = threadIdx.x;          // 64 threads
  float s = bd[0];
  for (int k = 0; k < 256; ++k) s += bf2f(h2f[b * 256 + k]) * Wd[k];
  for (int k = 0; k < 256; ++k) s += h2b[(size_t)b * 256 + k] * Wd[256 + k];
  out[b] = sigm(s);
}

// ---------------- host ----------------
extern "C" void kernel_launch(void* const* d_in, const int* in_sizes, int n_in,
                              void* d_out, int out_size, void* d_ws, size_t ws_size,
                              hipStream_t stream)
{
  (void)in_sizes; (void)n_in; (void)out_size;
  const int*   tokens = (const int*)d_in[0];
  const float* embed  = (const float*)d_in[1];
  const float* fw1_Wi = (const float*)d_in[2];
  const float* fw1_Wh = (const float*)d_in[3];
  const float* fw1_b  = (const float*)d_in[4];
  const float* bw1_Wi = (const float*)d_in[5];
  const float* bw1_Wh = (const float*)d_in[6];
  const float* bw1_b  = (const float*)d_in[7];
  const float* fw2_Wi = (const float*)d_in[8];
  const float* fw2_Wh = (const float*)d_in[9];
  const float* fw2_b  = (const float*)d_in[10];
  const float* bw2_Wi = (const float*)d_in[11];
  const float* bw2_Wh = (const float*)d_in[12];
  const float* bw2_b  = (const float*)d_in[13];
  const float* Wd     = (const float*)d_in[14];
  const float* bd     = (const float*)d_in[15];
  float* out = (float*)d_out;

  auto total_for = [](int S)->size_t{
    size_t fixed = 33554432ull + 67108864ull          // x1t, x2t
                 + 524288ull*2 + 1048576ull           // wipT
                 + 262144ull*3                        // w8 x3
                 + 12288ull                           // biases
                 + 131072ull + 49152ull               // cst1, hst1
                 + 65536ull + 24576ull                // cst2, hst2
                 + 32768ull + 65536ull + 65536ull;    // hst2bf, h2b, slack
    return fixed + 2ull * (size_t)S * 262144ull;      // xwf + xwb (f32)
  };
  int S = 256;
  while (S > 32 && total_for(S) > ws_size) S >>= 1;
  int NC = 1024 / S;

  char* ws = (char*)d_ws;
  size_t o = 0;
  auto alloc = [&](size_t sz){ size_t r = o; o += (sz + 255) & ~(size_t)255; return r; };
  short* x1t    = (short*)(ws + alloc(64ull * 1024 * 256 * 2));   // 32MB
  short* x2t    = (short*)(ws + alloc(64ull * 1024 * 512 * 2));   // 64MB
  float* xwf    = (float*)(ws + alloc((size_t)S * 262144ull));
  float* xwb    = (float*)(ws + alloc((size_t)S * 262144ull));
  short* wipT1f = (short*)(ws + alloc(256ull * 1024 * 2));
  short* wipT1b = (short*)(ws + alloc(256ull * 1024 * 2));
  short* wipT2f = (short*)(ws + alloc(512ull * 1024 * 2));
  u64*   w81f   = (u64*)(ws + alloc(262144ull));
  u64*   w81b   = (u64*)(ws + alloc(262144ull));
  u64*   w82f   = (u64*)(ws + alloc(262144ull));
  float* bp1f   = (float*)(ws + alloc(1024 * 4));
  float* bp1b   = (float*)(ws + alloc(1024 * 4));
  float* bp2f   = (float*)(ws + alloc(1024 * 4));
  float* cst1   = (float*)(ws + alloc(2ull * 64 * 256 * 4));      // 8 blks x 16 x 256
  char*  hst1   = (char*)(ws + alloc(8ull * 6144));
  float* cst2   = (float*)(ws + alloc(64ull * 256 * 4));          // 4 blks x 16 x 256
  char*  hst2   = (char*)(ws + alloc(4ull * 6144));
  short* hst2bf = (short*)(ws + alloc(64ull * 256 * 2));          // final layer-2 fwd h, [b][u] bf16
  float* h2b    = (float*)(ws + alloc(64ull * 256 * 4));

  // weight prep
  k_prep_wipT<<<128, 256, 0, stream>>>(fw1_Wi, wipT1f, 256);
  k_prep_wipT<<<128, 256, 0, stream>>>(bw1_Wi, wipT1b, 256);
  k_prep_wipT<<<256, 256, 0, stream>>>(fw2_Wi, wipT2f, 512);
  k_prep_bias<<<4, 256, 0, stream>>>(fw1_b, bp1f);
  k_prep_bias<<<4, 256, 0, stream>>>(bw1_b, bp1b);
  k_prep_bias<<<4, 256, 0, stream>>>(fw2_b, bp2f);
  k_prep_wht8<<<32, 256, 0, stream>>>(fw1_Wh, w81f);
  k_prep_wht8<<<32, 256, 0, stream>>>(bw1_Wh, w81b);
  k_prep_wht8<<<32, 256, 0, stream>>>(fw2_Wh, w82f);

  // embedding gather
  k_gather<<<4096, 256, 0, stream>>>(tokens, embed, x1t);

  dim3 ggrid(S / 2, 8);

  // ---- layer 1, chunked over time ----
  for (int c = 0; c < NC; ++c){
    int t0 = c * S;
    const short* Af = x1t + (size_t)t0 * 64 * 256;
    const short* Ab = x1t + (size_t)(1024 - (c + 1) * S) * 64 * 256;
    k_gemm<256><<<ggrid, 256, 0, stream>>>(Af, wipT1f, bp1f, xwf);
    k_gemm<256><<<ggrid, 256, 0, stream>>>(Ab, wipT1b, bp1b, xwb);
    k_recur8<1><<<8, 512, 0, stream>>>(xwf, xwb, w81f, w81b,
                                       x2t, cst1, hst1, t0, S, 1, c == 0);
  }

  // ---- layer 2 fwd, chunked ----
  for (int c = 0; c < NC; ++c){
    int t0 = c * S;
    const short* A2 = x2t + (size_t)t0 * 64 * 512;
    k_gemm<512><<<ggrid, 256, 0, stream>>>(A2, wipT2f, bp2f, xwf);
    k_recur8<0><<<4, 512, 0, stream>>>(xwf, xwf, w82f, w82f,
                                       hst2bf, cst2, hst2, t0, S, 0, c == 0);
  }

  // ---- layer 2 bwd = single step at t=1023 ----
  k_h2b<<<64, 256, 0, stream>>>(x2t, bw2_Wi, bw2_b, h2b);

  // ---- head ----
  k_logits<<<1, 64, 0, stream>>>(hst2bf, h2b, Wd, bd, out);
}

// Round 7
// 3609.076 us; speedup vs baseline: 2.4871x; 1.1869x over previous
//
#include <hip/hip_runtime.h>
#include <hip/hip_bf16.h>
#include <cstdint>
#include <cstddef>

typedef __attribute__((ext_vector_type(8))) short bf16x8;
typedef __attribute__((ext_vector_type(4))) short bf16x4;
typedef __attribute__((ext_vector_type(4))) float f32x4;
typedef __attribute__((ext_vector_type(4))) int   i32x4;
typedef __attribute__((ext_vector_type(8))) int   i32x8;
typedef unsigned long long u64;

#define LOG2E 1.442695041f

__device__ __forceinline__ float bf2f(short s){
  unsigned int u = ((unsigned int)(unsigned short)s) << 16;
  return __builtin_bit_cast(float, u);
}
__device__ __forceinline__ short f2bf(float f){
  return __builtin_bit_cast(short, __float2bfloat16(f));   // HW RNE cvt
}
// pre-scaled gate activations: zp = -log2e * z  (i,f,o),  zpp = +2*log2e * z (g)
__device__ __forceinline__ float sig_pre(float zp){
  return __builtin_amdgcn_rcpf(1.f + __builtin_amdgcn_exp2f(zp));
}
__device__ __forceinline__ float tanh_pre(float zpp){
  return 1.f - 2.f * __builtin_amdgcn_rcpf(1.f + __builtin_amdgcn_exp2f(zpp));
}
__device__ __forceinline__ float sigm(float x){ return sig_pre(-LOG2E * x); }
__device__ __forceinline__ float tanh_(float x){ return tanh_pre(2.f * LOG2E * x); }
__device__ __forceinline__ void wg_barrier(){
  asm volatile("s_waitcnt lgkmcnt(0)" ::: "memory");
  __builtin_amdgcn_s_barrier();
  asm volatile("" ::: "memory");
}
// 8-wave permutation: np = w*128 + gate*32 + ul  ->  orig = gate*256 + w*32 + ul
__device__ __forceinline__ int orig_col8(int np){
  int w = np >> 7, rem = np & 127, gate = rem >> 5, ul = rem & 31;
  return gate * 256 + w * 32 + ul;
}
// gate-wise pre-scale: i,f,o -> -log2e ; g -> +2log2e (gate order i,f,g,o)
__device__ __forceinline__ float gate_scale(int np){
  int gate = (np >> 5) & 3;
  return (gate == 2) ? (2.f * LOG2E) : (-LOG2E);
}
__device__ __forceinline__ char f2fp8(float x){
  int pk = __builtin_amdgcn_cvt_pk_fp8_f32(x, x, 0, false);
  return (char)(pk & 0xff);
}

// ---------------- prep kernels ----------------
__global__ void k_prep_wipT(const float* __restrict__ Wi, short* __restrict__ outT, int K){
  int idx = blockIdx.x * 256 + threadIdx.x;      // over 1024*K/8
  int kv = K >> 3;
  int np = idx / kv, k0 = (idx % kv) * 8;
  int oc = orig_col8(np);
  float sc = gate_scale(np);
  bf16x8 v;
  #pragma unroll
  for (int j = 0; j < 8; ++j) v[j] = f2bf(Wi[(size_t)(k0 + j) * 1024 + oc] * sc);
  *(bf16x8*)(outT + (size_t)np * K + k0) = v;
}

__global__ void k_prep_bias(const float* __restrict__ b, float* __restrict__ bp){
  int np = blockIdx.x * 256 + threadIdx.x;
  bp[np] = b[orig_col8(np)] * gate_scale(np);
}

// Wh [256,1024] f32 -> fp8 B-frags for 16x16x128 (pre-scaled)
__global__ void k_prep_wht8(const float* __restrict__ Wh, u64* __restrict__ w8){
  int idx = blockIdx.x * 256 + threadIdx.x;      // 8192
  int l = idx & 63, fk = idx >> 6;               // fk = wn*2 + kki
  int kki = fk & 1, wn = fk >> 1;
  int pc = wn * 16 + (l & 15);                   // permuted col
  int oc = orig_col8(pc);
  float sc = gate_scale(pc);
  int kbase = kki * 128 + ((l >> 4) << 5);
  u64* dst = w8 + (size_t)idx * 4;
  #pragma unroll
  for (int qq = 0; qq < 4; ++qq){
    u64 x = 0;
    #pragma unroll
    for (int j = 0; j < 8; ++j){
      unsigned int b = (unsigned char)f2fp8(Wh[(size_t)(kbase + qq * 8 + j) * 1024 + oc] * sc);
      x |= ((u64)b) << (8 * j);
    }
    dst[qq] = x;
  }
}

// embedding gather
__global__ void k_gather(const int* __restrict__ tokens, const float* __restrict__ embed,
                         short* __restrict__ x1t){
  int v = blockIdx.x * 256 + threadIdx.x;
  const int total = 64 * 1024 * 256 / 4;
  for (; v < total; v += gridDim.x * 256){
    int e = v * 4;
    int row = e >> 8, k = e & 255;
    int t = row >> 6, b = row & 63;
    int tok = tokens[b * 1024 + t];
    f32x4 f = *(const f32x4*)(embed + (size_t)tok * 256 + k);
    bf16x4 o4;
    #pragma unroll
    for (int j = 0; j < 4; ++j) o4[j] = f2bf(f[j]);
    *(bf16x4*)(x1t + e) = o4;
  }
}

// ---------------- GEMM tile body (shared standalone / fused) ----------------
template<int K>
__device__ __forceinline__ void gemm_tile(const short* __restrict__ A, const short* __restrict__ BT,
                                          const float* __restrict__ bias, float* __restrict__ xw,
                                          int bx, int by, short* ldsA, short* ldsB, int tid){
  int l = tid & 63, wid = tid >> 6, wm = wid >> 1, wn = wid & 1;
  int M0 = bx * 128, N0 = by * 128;
  f32x4 acc[4][4] = {};
  for (int kt = 0; kt < K / 64; ++kt){
    __syncthreads();
    for (int i = tid; i < 1024; i += 256){
      int row = i >> 3, seg = i & 7;
      *(bf16x8*)&ldsA[row * 72 + seg * 8] = *(const bf16x8*)&A[(size_t)(M0 + row) * K + kt * 64 + seg * 8];
      *(bf16x8*)&ldsB[row * 72 + seg * 8] = *(const bf16x8*)&BT[(size_t)(N0 + row) * K + kt * 64 + seg * 8];
    }
    __syncthreads();
    #pragma unroll
    for (int kk = 0; kk < 2; ++kk){
      int koff = kk * 32 + ((l >> 4) << 3);
      bf16x8 af[4], bfm[4];
      #pragma unroll
      for (int mt = 0; mt < 4; ++mt) af[mt] = *(const bf16x8*)&ldsA[(wm * 64 + mt * 16 + (l & 15)) * 72 + koff];
      #pragma unroll
      for (int nt = 0; nt < 4; ++nt) bfm[nt] = *(const bf16x8*)&ldsB[(wn * 64 + nt * 16 + (l & 15)) * 72 + koff];
      #pragma unroll
      for (int mt = 0; mt < 4; ++mt)
        #pragma unroll
        for (int nt = 0; nt < 4; ++nt)
          acc[mt][nt] = __builtin_amdgcn_mfma_f32_16x16x32_bf16(af[mt], bfm[nt], acc[mt][nt], 0, 0, 0);
    }
  }
  int t = bx * 2 + wm;   // chunk-local t
  #pragma unroll
  for (int mt = 0; mt < 4; ++mt){
    #pragma unroll
    for (int nt = 0; nt < 4; ++nt){
      int ng = (N0 >> 4) + wn * 4 + nt;
      float bs = bias[ng * 16 + (l & 15)];
      f32x4 ov;
      #pragma unroll
      for (int r = 0; r < 4; ++r) ov[r] = acc[mt][nt][r] + bs;
      *(f32x4*)&xw[((size_t)(t * 4 + mt) * 64 + ng) * 256 + l * 4] = ov;
    }
  }
}

template<int K>
__global__ __launch_bounds__(256)
void k_gemm(const short* __restrict__ A, const short* __restrict__ BT,
            const float* __restrict__ bias, float* __restrict__ xw){
  __shared__ short ldsA[128 * 72];
  __shared__ short ldsB[128 * 72];
  gemm_tile<K>(A, BT, bias, xw, blockIdx.x, blockIdx.y, ldsA, ldsB, threadIdx.x);
}

#define MFMA_SC(a, b, c) __builtin_amdgcn_mfma_scale_f32_16x16x128_f8f6f4( \
    (a), (b), (c), 0, 0, 0, 0x7f7f7f7f, 0, 0x7f7f7f7f)

// ---------------- fused recur + next-chunk GEMM ----------------
// blocks [0,R): recurrence (8 waves, MX-fp8 K=128, 2 waves/SIMD)
// blocks [R, R+G): GEMM tiles of the NEXT chunk (2 x 256-thread sub-tiles per WG)
template<int WRITE_SEQ, int GK>
__global__ __launch_bounds__(512, 2)
void k_fused(const float* __restrict__ xw_f, const float* __restrict__ xw_b,
             const u64* __restrict__ w8_f, const u64* __restrict__ w8_b,
             short* __restrict__ outp, float* __restrict__ cstate, char* __restrict__ hstate,
             int t0, int S, int two_dirs, int first, int R,
             const short* __restrict__ gA0, const short* __restrict__ gA1,
             const short* __restrict__ gBT0, const short* __restrict__ gBT1,
             const float* __restrict__ gb0, const float* __restrict__ gb1,
             float* __restrict__ gxw0, float* __restrict__ gxw1)
{
  extern __shared__ char smem[];
  if ((int)blockIdx.x >= R){
    int sub = threadIdx.x >> 8;
    int tid = threadIdx.x & 255;
    int tile = ((int)blockIdx.x - R) * 2 + sub;
    int tpj = 4 * S;                       // tiles per job
    int job = tile / tpj, tt = tile % tpj; // grid sized exactly -> job valid
    short* ldsA = (short*)(smem + sub * 36864);
    short* ldsB = ldsA + 128 * 72;
    gemm_tile<GK>(job ? gA1 : gA0, job ? gBT1 : gBT0, job ? gb1 : gb0,
                  job ? gxw1 : gxw0, tt >> 3, tt & 7, ldsA, ldsB, tid);
    return;
  }

  // ---- recurrence ----
  char* ldsH = smem;                       // 2 x 6144B double buffer
  int g = blockIdx.x;
  int d  = two_dirs ? (g >> 2) : 0;
  int cb = two_dirs ? (g & 3) : g;
  int blk = g;
  const float* xw = d ? xw_b : xw_f;
  const u64*  w8  = d ? w8_b : w8_f;
  int tid = threadIdx.x, w = tid >> 6, l = tid & 63;

  // B fragments (fp8, K=128) fully in registers
  i32x8 Breg[16];
  #pragma unroll
  for (int n = 0; n < 8; ++n)
    #pragma unroll
    for (int kki = 0; kki < 2; ++kki){
      const i32x4* bp = (const i32x4*)(w8 + ((size_t)((w * 8 + n) * 2 + kki) * 64 + l) * 4);
      Breg[n * 2 + kki] = __builtin_shufflevector(bp[0], bp[1], 0,1,2,3,4,5,6,7);
    }

  f32x4 cst[2];
  if (first){
    if (tid < 384) *(i32x4*)(ldsH + tid * 16) = i32x4{0,0,0,0};
    cst[0] = f32x4{0.f,0.f,0.f,0.f};
    cst[1] = f32x4{0.f,0.f,0.f,0.f};
  } else {
    const char* hsrc = hstate + (size_t)blk * 6144;
    if (tid < 384) *(i32x4*)(ldsH + tid * 16) = *(const i32x4*)(hsrc + tid * 16);
    #pragma unroll
    for (int uh = 0; uh < 2; ++uh)
      #pragma unroll
      for (int r = 0; r < 4; ++r){
        int batch = ((l >> 4) << 2) + r, unit = w * 32 + uh * 16 + (l & 15);
        cst[uh][r] = cstate[((size_t)blk * 16 + batch) * 256 + unit];
      }
  }
  __syncthreads();

  long xwStep = (d ? -1l : 1l) * 4 * 64 * 256;
  const float* xwCur = xw + ((size_t)((d ? (S - 1) : 0) * 4 + cb) * 64) * 256;
  f32x4 px[8];
  #pragma unroll
  for (int n = 0; n < 8; ++n)
    px[n] = *(const f32x4*)&xwCur[((w * 8 + n) * 64 + l) * 4];

  char* seqB = nullptr;
  long seqStepB = (d ? -1l : 1l) * 64 * 512 * 2;
  if (WRITE_SEQ)
    seqB = (char*)(outp + ((long)(d ? (1023 - t0) : t0) * 64 + cb * 16 + ((l >> 4) << 2)) * 512
                        + d * 256 + w * 32 + (l & 15));

  const int aOff = (l & 15) * 48 + ((l >> 4) * 768);
  const int hOff = w * 768 + ((l >> 4) << 2) * 48 + (l & 15);

  int p = 0;
  #pragma unroll 1
  for (int s = 0; s < S; ++s){
    const float* xwNext = (s + 1 < S) ? (xwCur + xwStep) : xwCur;

    const char* aB = ldsH + p * 6144 + aOff;
    i32x4 a0 = *(const i32x4*)(aB);
    i32x4 a1 = *(const i32x4*)(aB + 16);
    i32x4 a2 = *(const i32x4*)(aB + 3072);
    i32x4 a3 = *(const i32x4*)(aB + 3088);
    i32x8 af0 = __builtin_shufflevector(a0, a1, 0,1,2,3,4,5,6,7);
    i32x8 af1 = __builtin_shufflevector(a2, a3, 0,1,2,3,4,5,6,7);

    f32x4 acc[8];
    // block A: even tiles (uh=0), C-operand = px (no copies)
    #pragma unroll
    for (int n = 0; n < 8; n += 2)
      acc[n] = MFMA_SC(af1, Breg[n * 2 + 1], MFMA_SC(af0, Breg[n * 2 + 0], px[n]));
    // refill even px (latency hidden under block B + gates)
    #pragma unroll
    for (int n = 0; n < 8; n += 2)
      px[n] = *(const f32x4*)&xwNext[((w * 8 + n) * 64 + l) * 4];
    // block B: odd tiles (uh=1)
    #pragma unroll
    for (int n = 1; n < 8; n += 2)
      acc[n] = MFMA_SC(af1, Breg[n * 2 + 1], MFMA_SC(af0, Breg[n * 2 + 0], px[n]));

    char* hw = ldsH + (p ^ 1) * 6144 + hOff;
    // gates uh=0 (even accs — ready; overlaps block B in scheduler)
    #pragma unroll
    for (int uh = 0; uh < 2; ++uh){
      if (uh == 1){
        // refill odd px after their C-operand use
        #pragma unroll
        for (int n = 1; n < 8; n += 2)
          px[n] = *(const f32x4*)&xwNext[((w * 8 + n) * 64 + l) * 4];
      }
      #pragma unroll
      for (int r = 0; r < 4; ++r){
        float ii = sig_pre(acc[0 + uh][r]);
        float ff = sig_pre(acc[2 + uh][r]);
        float gg = tanh_pre(acc[4 + uh][r]);
        float oo = sig_pre(acc[6 + uh][r]);
        float cc = ff * cst[uh][r] + ii * gg;
        cst[uh][r] = cc;
        float hh = oo * tanh_(cc);
        *(char*)(hw + r * 48 + uh * 16) = f2fp8(hh);
        if (WRITE_SEQ){
          *(short*)(seqB + uh * 32 + r * 1024) = f2bf(hh);
        } else if (s == S - 1){
          outp[((size_t)cb * 16 + ((l >> 4) << 2) + r) * 256 + w * 32 + uh * 16 + (l & 15)] = f2bf(hh);
        }
      }
    }
    wg_barrier();   // single barrier per step (h double-buffered)
    p ^= 1;
    if (WRITE_SEQ) seqB += seqStepB;
    xwCur = xwNext;
  }

  {
    char* hdst = hstate + (size_t)blk * 6144;
    if (tid < 384) *(i32x4*)(hdst + tid * 16) = *(const i32x4*)(ldsH + p * 6144 + tid * 16);
  }
  #pragma unroll
  for (int uh = 0; uh < 2; ++uh)
    #pragma unroll
    for (int r = 0; r < 4; ++r){
      int batch = ((l >> 4) << 2) + r, unit = w * 32 + uh * 16 + (l & 15);
      cstate[((size_t)blk * 16 + batch) * 256 + unit] = cst[uh][r];
    }
}

// ---------------- layer-2 bwd single step ----------------
__global__ void k_h2b(const short* __restrict__ x2t, const float* __restrict__ Wi,
                      const float* __restrict__ bias, float* __restrict__ h2b){
  __shared__ float xr[512];
  int b = blockIdx.x, tid = threadIdx.x;
  for (int i = tid; i < 512; i += 256) xr[i] = bf2f(x2t[((size_t)1023 * 64 + b) * 512 + i]);
  __syncthreads();
  int u = tid;
  float s0 = bias[u], s2 = bias[512 + u], s3 = bias[768 + u];
  for (int k = 0; k < 512; ++k){
    float x = xr[k];
    const float* wr = Wi + (size_t)k * 1024;
    s0 += x * wr[u];
    s2 += x * wr[512 + u]; s3 += x * wr[768 + u];
  }
  float cc = sigm(s0) * tanh_(s2);          // c0 = 0 -> f-term drops
  float hh = sigm(s3) * tanh_(cc);
  h2b[(size_t)b * 256 + u] = hh;
}

__global__ void k_logits(const short* __restrict__ h2f, const float* __restrict__ h2b,
                         const float* __restrict__ Wd, const float* __restrict__ bd,
                         float* __restrict__ out){
  int b = threadIdx.x;          // 64 threads
  float s = bd[0];
  for (int k = 0; k < 256; ++k) s += bf2f(h2f[b * 256 + k]) * Wd[k];
  for (int k = 0; k < 256; ++k) s += h2b[(size_t)b * 256 + k] * Wd[256 + k];
  out[b] = sigm(s);
}

// ---------------- host ----------------
extern "C" void kernel_launch(void* const* d_in, const int* in_sizes, int n_in,
                              void* d_out, int out_size, void* d_ws, size_t ws_size,
                              hipStream_t stream)
{
  (void)in_sizes; (void)n_in; (void)out_size;
  const int*   tokens = (const int*)d_in[0];
  const float* embed  = (const float*)d_in[1];
  const float* fw1_Wi = (const float*)d_in[2];
  const float* fw1_Wh = (const float*)d_in[3];
  const float* fw1_b  = (const float*)d_in[4];
  const float* bw1_Wi = (const float*)d_in[5];
  const float* bw1_Wh = (const float*)d_in[6];
  const float* bw1_b  = (const float*)d_in[7];
  const float* fw2_Wi = (const float*)d_in[8];
  const float* fw2_Wh = (const float*)d_in[9];
  const float* fw2_b  = (const float*)d_in[10];
  const float* bw2_Wi = (const float*)d_in[11];
  const float* bw2_Wh = (const float*)d_in[12];
  const float* bw2_b  = (const float*)d_in[13];
  const float* Wd     = (const float*)d_in[14];
  const float* bd     = (const float*)d_in[15];
  float* out = (float*)d_out;

  auto total_for = [](int S)->size_t{
    size_t fixed = 33554432ull + 67108864ull          // x1t, x2t
                 + 524288ull*2 + 1048576ull           // wipT
                 + 262144ull*3                        // w8 x3
                 + 12288ull                           // biases
                 + 131072ull + 49152ull               // cst1, hst1
                 + 65536ull + 24576ull                // cst2, hst2
                 + 32768ull + 65536ull + 65536ull;    // hst2bf, h2b, slack
    return fixed + 4ull * (size_t)S * 262144ull;      // 4 xw buffers (f32, dbuf)
  };
  int S = 256;
  while (S > 32 && total_for(S) > ws_size) S >>= 1;
  int NC = 1024 / S;

  char* ws = (char*)d_ws;
  size_t o = 0;
  auto alloc = [&](size_t sz){ size_t r = o; o += (sz + 255) & ~(size_t)255; return r; };
  short* x1t    = (short*)(ws + alloc(64ull * 1024 * 256 * 2));   // 32MB
  short* x2t    = (short*)(ws + alloc(64ull * 1024 * 512 * 2));   // 64MB
  float* xf[2], *xb[2];
  xf[0] = (float*)(ws + alloc((size_t)S * 262144ull));
  xf[1] = (float*)(ws + alloc((size_t)S * 262144ull));
  xb[0] = (float*)(ws + alloc((size_t)S * 262144ull));
  xb[1] = (float*)(ws + alloc((size_t)S * 262144ull));
  short* wipT1f = (short*)(ws + alloc(256ull * 1024 * 2));
  short* wipT1b = (short*)(ws + alloc(256ull * 1024 * 2));
  short* wipT2f = (short*)(ws + alloc(512ull * 1024 * 2));
  u64*   w81f   = (u64*)(ws + alloc(262144ull));
  u64*   w81b   = (u64*)(ws + alloc(262144ull));
  u64*   w82f   = (u64*)(ws + alloc(262144ull));
  float* bp1f   = (float*)(ws + alloc(1024 * 4));
  float* bp1b   = (float*)(ws + alloc(1024 * 4));
  float* bp2f   = (float*)(ws + alloc(1024 * 4));
  float* cst1   = (float*)(ws + alloc(2ull * 64 * 256 * 4));
  char*  hst1   = (char*)(ws + alloc(8ull * 6144));
  float* cst2   = (float*)(ws + alloc(64ull * 256 * 4));
  char*  hst2   = (char*)(ws + alloc(4ull * 6144));
  short* hst2bf = (short*)(ws + alloc(64ull * 256 * 2));
  float* h2b    = (float*)(ws + alloc(64ull * 256 * 4));

  const int LDS_FUSED = 73728;
  hipFuncSetAttribute((const void*)&k_fused<1,256>, hipFuncAttributeMaxDynamicSharedMemorySize, LDS_FUSED);
  hipFuncSetAttribute((const void*)&k_fused<0,512>, hipFuncAttributeMaxDynamicSharedMemorySize, LDS_FUSED);

  // weight prep (pre-scaled)
  k_prep_wipT<<<128, 256, 0, stream>>>(fw1_Wi, wipT1f, 256);
  k_prep_wipT<<<128, 256, 0, stream>>>(bw1_Wi, wipT1b, 256);
  k_prep_wipT<<<256, 256, 0, stream>>>(fw2_Wi, wipT2f, 512);
  k_prep_bias<<<4, 256, 0, stream>>>(fw1_b, bp1f);
  k_prep_bias<<<4, 256, 0, stream>>>(bw1_b, bp1b);
  k_prep_bias<<<4, 256, 0, stream>>>(fw2_b, bp2f);
  k_prep_wht8<<<32, 256, 0, stream>>>(fw1_Wh, w81f);
  k_prep_wht8<<<32, 256, 0, stream>>>(bw1_Wh, w81b);
  k_prep_wht8<<<32, 256, 0, stream>>>(fw2_Wh, w82f);

  k_gather<<<4096, 256, 0, stream>>>(tokens, embed, x1t);

  dim3 ggrid(S / 2, 8);

  // chunk-0 input projections (exposed)
  k_gemm<256><<<ggrid, 256, 0, stream>>>(x1t, wipT1f, bp1f, xf[0]);
  k_gemm<256><<<ggrid, 256, 0, stream>>>(x1t + (size_t)(1024 - S) * 64 * 256, wipT1b, bp1b, xb[0]);

  // ---- layer 1: fused recur(c) + gemm(c+1) ----
  for (int c = 0; c < NC; ++c){
    int cur = c & 1, nxt = cur ^ 1;
    int njobs = (c + 1 < NC) ? 2 : 0;
    int G = njobs * 2 * S;
    const short* gA0 = x1t + (size_t)(c + 1) * S * 64 * 256;
    const short* gA1 = x1t + (size_t)(1024 - (size_t)(c + 2) * S) * 64 * 256;
    if (njobs == 0){ gA0 = x1t; gA1 = x1t; }
    k_fused<1,256><<<8 + G, 512, LDS_FUSED, stream>>>(
        xf[cur], xb[cur], w81f, w81b, x2t, cst1, hst1, c * S, S, 1, c == 0, 8,
        gA0, gA1, wipT1f, wipT1b, bp1f, bp1b, xf[nxt], xb[nxt]);
  }

  // ---- layer 2 fwd: chunk-0 gemm exposed, then fused ----
  k_gemm<512><<<ggrid, 256, 0, stream>>>(x2t, wipT2f, bp2f, xf[0]);
  for (int c = 0; c < NC; ++c){
    int cur = c & 1, nxt = cur ^ 1;
    int njobs = (c + 1 < NC) ? 1 : 0;
    int G = njobs * 2 * S;
    const short* gA0 = (njobs ? (const short*)(x2t + (size_t)(c + 1) * S * 64 * 512) : (const short*)x2t);
    k_fused<0,512><<<4 + G, 512, LDS_FUSED, stream>>>(
        xf[cur], xf[cur], w82f, w82f, hst2bf, cst2, hst2, c * S, S, 0, c == 0, 4,
        gA0, gA0, wipT2f, wipT2f, bp2f, bp2f, xf[nxt], xf[nxt]);
  }

  // ---- layer 2 bwd = single step at t=1023 ----
  k_h2b<<<64, 256, 0, stream>>>(x2t, bw2_Wi, bw2_b, h2b);

  // ---- head ----
  k_logits<<<1, 64, 0, stream>>>(hst2bf, h2b, Wd, bd, out);
}